// Round 8
// baseline (1198.472 us; speedup 1.0000x reference)
//
#include <hip/hip_runtime.h>
#include <math.h>

#define B_      16
#define NH      32
#define NKV     8
#define HD      128
#define GQ      4
#define LWIN    4096
#define BS      16
#define MAXB    385
#define HIDDEN  4096
#define QKV_COLS 6144
#define TAB_N   4100
#define T_CUR   4080      // window index of the current (new) token
#define KS      64        // k-rows per gemm split slice
#define NSPLIT  64        // number of k slices (4096/KS)
#define NCHUNK  8         // 512-token chunks
#define SCALE   0.088388347648318447f   // 128^-0.5
#define LOG1E4  9.210340371976184
#define TWO_PI  6.283185307179586
#define INV_2PI 0.15915494309189535

typedef float f4v __attribute__((ext_vector_type(4)));

// ---------------- K0: trig tables + zero patched blocks ----------------
__global__ void k_table(float* __restrict__ ctab, float* __restrict__ stab,
                        float* __restrict__ pk, float* __restrict__ pv) {
  int idx = blockIdx.x * 256 + threadIdx.x;
  if (idx < 64 * (TAB_N / 4)) {
    int d = idx / (TAB_N / 4);
    int q = idx - d * (TAB_N / 4);
    int i0 = q * 4;
    double f = exp(-(double)d / 64.0 * LOG1E4);
    double a = (double)(i0 - 1) * f;
    double rev = a * INV_2PI;
    rev -= rint(rev);
    float r = (float)(rev * TWO_PI);
    float c = cosf(r), s = sinf(r);
    float ff = (float)f;
    float cf = cosf(ff), sf = sinf(ff);
    int base = d * TAB_N + i0;
    ctab[base] = c; stab[base] = s;
#pragma unroll
    for (int j = 1; j < 4; j++) {
      float cn = c * cf - s * sf;
      float sn = s * cf + c * sf;
      c = cn; s = sn;
      ctab[base + j] = c; stab[base + j] = s;
    }
  }
  int nz = B_ * NKV * HD * BS;
  for (int z = idx; z < nz; z += gridDim.x * 256) { pk[z] = 0.f; pv[z] = 0.f; }
}

// ---------------- split-K skinny GEMM partial: part[ky][b][n] ----------------
// DIAGNOSTIC: reps>1 re-executes identical work (idempotent stores).
__global__ __launch_bounds__(128) void k_gemm_part(
    const float* __restrict__ X, const float* __restrict__ W,
    float* __restrict__ part, int K, int ncols, int reps) {
  int tid = threadIdx.x;
  int k0 = blockIdx.y * KS;
  int n4 = (blockIdx.x * 128 + tid) * 4;
  for (int rep = 0; rep < reps; rep++) {
    f4v acc[B_];
#pragma unroll
    for (int b = 0; b < B_; b++) acc[b] = (f4v){0.f, 0.f, 0.f, 0.f};
    const float* wp = W + (size_t)k0 * ncols + n4;
    const float* xp = X + k0;
#pragma unroll 8
    for (int kk = 0; kk < KS; kk++) {
      f4v w = __builtin_nontemporal_load((const f4v*)&wp[(size_t)kk * ncols]);
#pragma unroll
      for (int b = 0; b < B_; b++) {
        float x = xp[b * K + kk];
        acc[b][0] = fmaf(x, w[0], acc[b][0]);
        acc[b][1] = fmaf(x, w[1], acc[b][1]);
        acc[b][2] = fmaf(x, w[2], acc[b][2]);
        acc[b][3] = fmaf(x, w[3], acc[b][3]);
      }
    }
    float* pp = part + (size_t)blockIdx.y * B_ * ncols + n4;
#pragma unroll
    for (int b = 0; b < B_; b++) *(f4v*)&pp[(size_t)b * ncols] = acc[b];
  }
}

// ------------- reduce qkv partials + RoPE + scatter q / patched k,v -------------
__global__ __launch_bounds__(256) void k_qkv_finish(
    const float* __restrict__ part, const int* __restrict__ positions,
    const float* __restrict__ ctab, const float* __restrict__ stab,
    float* __restrict__ qout, float* __restrict__ pk, float* __restrict__ pv) {
  int idx = blockIdx.x * 256 + threadIdx.x;
  int b = idx / 3584;
  int u = idx - b * 3584;
  if (b >= B_) return;
  if (u < 2560) {                       // rope pair units: h in [0,40), j in [0,64)
    int h = u >> 6, j = u & 63;
    int c1 = h * 128 + j;
    int c2 = c1 + 64;
    float s1 = 0.f, s2 = 0.f;
#pragma unroll 8
    for (int ky = 0; ky < NSPLIT; ky++) {
      const float* p = part + ((size_t)ky * B_ + b) * QKV_COLS;
      s1 += p[c1];
      s2 += p[c2];
    }
    int pos = min(positions[b], LWIN - 1);
    float c = ctab[j * TAB_N + pos + 1];
    float s = stab[j * TAB_N + pos + 1];
    float o1 = s1 * c - s2 * s;
    float o2 = s2 * c + s1 * s;
    if (h < NH) {
      qout[b * HIDDEN + c1] = o1;
      qout[b * HIDDEN + c2] = o2;
    } else {
      int kv = h - NH;
      pk[((b * NKV + kv) * HD + j) * BS] = o1;
      pk[((b * NKV + kv) * HD + j + 64) * BS] = o2;
    }
  } else {                              // v units
    int vi = u - 2560;
    int kv = vi >> 7, d = vi & 127;
    int col = 5120 + vi;
    float s = 0.f;
#pragma unroll 8
    for (int ky = 0; ky < NSPLIT; ky++)
      s += part[((size_t)ky * B_ + b) * QKV_COLS + col];
    pv[((b * NKV + kv) * HD + d) * BS] = s;
  }
}

// ---------------- paged attention (R5 structure, known 133us) ----------------
// DIAGNOSTIC: reps>1 re-executes identical work (idempotent stores).
__global__ __launch_bounds__(128) void k_attn(
    const float* __restrict__ kc, const float* __restrict__ vc,
    const int* __restrict__ bt, const float* __restrict__ qbuf,
    const float* __restrict__ pk, const float* __restrict__ pv,
    const float* __restrict__ ctab, const float* __restrict__ stab,
    float* __restrict__ partial, int reps) {
  __shared__ __align__(16) float qT[HD][GQ];      // [d][g]
  __shared__ __align__(16) float p_s[512][GQ];    // chunk-local probs
  __shared__ float redm[2][GQ];
  __shared__ float redl[2][GQ];
  __shared__ const float* kbase[32];
  __shared__ const float* vbase[32];

  int bx = blockIdx.x;
  int b = bx & 15, kv = bx >> 4;
  int chunk = blockIdx.y;   // 0..7, 512 tokens each
  int tid = threadIdx.x;
  int lane = tid & 63, wave = tid >> 6;

  for (int i = tid; i < GQ * HD; i += 128) {
    int g = i >> 7, d = i & 127;
    qT[d][g] = qbuf[b * HIDDEN + (kv * GQ + g) * HD + d];
  }
  if (tid < 32) {
    int tb = chunk * 32 + tid;          // global 16-token block index
    if (tb == 255) {
      kbase[tid] = pk + (size_t)(b * NKV + kv) * (HD * BS);
      vbase[tid] = pv + (size_t)(b * NKV + kv) * (HD * BS);
    } else {
      int lg = (tb == 0) ? 0 : (129 + tb);
      size_t off = ((size_t)bt[b * MAXB + lg] * NKV + kv) * (HD * BS);
      kbase[tid] = kc + off;
      vbase[tid] = vc + off;
    }
  }

  for (int rep = 0; rep < reps; rep++) {
    __syncthreads();   // pointers ready / previous rep's phase B done

    // ---- phase A: scores, 256 tokens per wave ----
    int blk_i = lane & 15, qq = lane >> 4;
    int t0 = chunk * 512 + wave * 256 + blk_i * 16 + qq * 4;
    const float* kb = kbase[wave * 16 + blk_i] + qq * 4;
    bool rot = (t0 >= 16) && (t0 < T_CUR);
    const float* ctp = ctab + t0;
    const float* stp = stab + t0;

    float sc[GQ][4];
#pragma unroll
    for (int g = 0; g < GQ; g++)
#pragma unroll
      for (int c = 0; c < 4; c++) sc[g][c] = 0.f;

#pragma unroll 8
    for (int d = 0; d < 64; d++) {
      f4v k1 = __builtin_nontemporal_load((const f4v*)(kb + d * BS));
      f4v k2 = __builtin_nontemporal_load((const f4v*)(kb + (d + 64) * BS));
      float4 cv = *(const float4*)(ctp + d * TAB_N);
      float4 sv = *(const float4*)(stp + d * TAB_N);
      float4 q1 = *(const float4*)&qT[d][0];
      float4 q2 = *(const float4*)&qT[d + 64][0];
      float cc[4] = {rot ? cv.x : 1.f, rot ? cv.y : 1.f, rot ? cv.z : 1.f, rot ? cv.w : 1.f};
      float ss[4] = {rot ? sv.x : 0.f, rot ? sv.y : 0.f, rot ? sv.z : 0.f, rot ? sv.w : 0.f};
      float qg1[4] = {q1.x, q1.y, q1.z, q1.w};
      float qg2[4] = {q2.x, q2.y, q2.z, q2.w};
#pragma unroll
      for (int c = 0; c < 4; c++) {
        float r1 = k1[c] * cc[c] - k2[c] * ss[c];
        float r2 = k2[c] * cc[c] + k1[c] * ss[c];
#pragma unroll
        for (int g = 0; g < GQ; g++)
          sc[g][c] = fmaf(qg1[g], r1, fmaf(qg2[g], r2, sc[g][c]));
      }
    }

    // scale + validity mask + per-wave max
    float mloc[GQ];
#pragma unroll
    for (int g = 0; g < GQ; g++) {
      float m = -3e38f;
#pragma unroll
      for (int c = 0; c < 4; c++) {
        float s = (t0 + c <= T_CUR) ? sc[g][c] * SCALE : -3e38f;
        sc[g][c] = s;
        m = fmaxf(m, s);
      }
#pragma unroll
      for (int off = 1; off < 64; off <<= 1) m = fmaxf(m, __shfl_xor(m, off, 64));
      mloc[g] = m;
    }
    if (lane == 0) {
#pragma unroll
      for (int g = 0; g < GQ; g++) redm[wave][g] = mloc[g];
    }
    __syncthreads();
    float mb[GQ];
#pragma unroll
    for (int g = 0; g < GQ; g++) mb[g] = fmaxf(redm[0][g], redm[1][g]);

    // probs + per-wave sums
    float4 prc[4];
    float ls[GQ] = {0.f, 0.f, 0.f, 0.f};
#pragma unroll
    for (int c = 0; c < 4; c++) {
      float p0 = __expf(sc[0][c] - mb[0]);
      float p1 = __expf(sc[1][c] - mb[1]);
      float p2 = __expf(sc[2][c] - mb[2]);
      float p3 = __expf(sc[3][c] - mb[3]);
      ls[0] += p0; ls[1] += p1; ls[2] += p2; ls[3] += p3;
      prc[c] = make_float4(p0, p1, p2, p3);
    }
#pragma unroll
    for (int g = 0; g < GQ; g++) {
      float v = ls[g];
#pragma unroll
      for (int off = 1; off < 64; off <<= 1) v += __shfl_xor(v, off, 64);
      ls[g] = v;
    }
    if (lane == 0) {
#pragma unroll
      for (int g = 0; g < GQ; g++) redl[wave][g] = ls[g];
    }
    int trow = t0 - chunk * 512;
#pragma unroll
    for (int c = 0; c < 4; c++) *(float4*)&p_s[trow + c][0] = prc[c];
    __syncthreads();   // p_s / redl complete

    // ---- phase B: PV, 64B/lane coalesced V reads, no barriers ----
    float acc0 = 0.f, acc1 = 0.f, acc2 = 0.f, acc3 = 0.f;
    int d_own = tid;   // 0..127
#pragma unroll 2
    for (int tb = 0; tb < 32; tb++) {
      const float* vb = vbase[tb] + d_own * BS;
      f4v v0 = __builtin_nontemporal_load((const f4v*)(vb));
      f4v v1 = __builtin_nontemporal_load((const f4v*)(vb + 4));
      f4v v2 = __builtin_nontemporal_load((const f4v*)(vb + 8));
      f4v v3 = __builtin_nontemporal_load((const f4v*)(vb + 12));
      float vv[16] = {v0[0], v0[1], v0[2], v0[3], v1[0], v1[1], v1[2], v1[3],
                      v2[0], v2[1], v2[2], v2[3], v3[0], v3[1], v3[2], v3[3]};
      const float* pp = &p_s[tb * 16][0];
#pragma unroll
      for (int j = 0; j < 16; j++) {
        float4 pj = *(const float4*)(pp + j * GQ);
        acc0 = fmaf(pj.x, vv[j], acc0);
        acc1 = fmaf(pj.y, vv[j], acc1);
        acc2 = fmaf(pj.z, vv[j], acc2);
        acc3 = fmaf(pj.w, vv[j], acc3);
      }
    }

    int pid = b * NKV + kv;
    float* pw = partial + ((size_t)pid * NCHUNK + chunk) * (GQ * 130);
    pw[0 * 130 + 2 + d_own] = acc0;
    pw[1 * 130 + 2 + d_own] = acc1;
    pw[2 * 130 + 2 + d_own] = acc2;
    pw[3 * 130 + 2 + d_own] = acc3;
    if (tid == 0) {
#pragma unroll
      for (int g = 0; g < GQ; g++) {
        pw[g * 130 + 0] = mb[g];
        pw[g * 130 + 1] = redl[0][g] + redl[1][g];
      }
    }
  }
}

// ---------------- combine chunk partials -> attn[b][h*128+d] ----------------
__global__ __launch_bounds__(512) void k_attn_combine(
    const float* __restrict__ partial, float* __restrict__ attn) {
  int pair = blockIdx.x;
  int tid = threadIdx.x;
  int g = tid >> 7, d = tid & 127;
  const float* pb = partial + (size_t)pair * NCHUNK * (GQ * 130) + g * 130;
  float M = -3e38f;
#pragma unroll
  for (int c = 0; c < NCHUNK; c++) M = fmaxf(M, pb[c * (GQ * 130)]);
  float L = 0.f, val = 0.f;
#pragma unroll
  for (int c = 0; c < NCHUNK; c++) {
    float m = pb[c * (GQ * 130)];
    float l = pb[c * (GQ * 130) + 1];
    float a = pb[c * (GQ * 130) + 2 + d];
    float w = __expf(m - M);
    L += l * w;
    val = fmaf(a, w, val);
  }
  int b = pair >> 3, kv = pair & 7;
  attn[b * HIDDEN + (kv * GQ + g) * HD + d] = val / L;
}

// ---------------- reduce w_o partials -> out ----------------
__global__ __launch_bounds__(256) void k_reduce_out(
    const float* __restrict__ part, float* __restrict__ out) {
  int idx = blockIdx.x * 256 + threadIdx.x;
  int b = idx >> 12, n = idx & 4095;
  float s = 0.f;
#pragma unroll 8
  for (int ky = 0; ky < NSPLIT; ky++)
    s += part[((size_t)ky * B_ + b) * HIDDEN + n];
  out[idx] = s;
}

extern "C" void kernel_launch(void* const* d_in, const int* in_sizes, int n_in,
                              void* d_out, int out_size, void* d_ws, size_t ws_size,
                              hipStream_t stream) {
  const int*   positions = (const int*)d_in[0];
  const float* hs        = (const float*)d_in[1];
  const float* kc        = (const float*)d_in[2];
  const float* vc        = (const float*)d_in[3];
  const int*   bt        = (const int*)d_in[4];
  const float* w_qkv     = (const float*)d_in[6];
  const float* w_o       = (const float*)d_in[7];
  float* out = (float*)d_out;

  float* ws    = (float*)d_ws;
  float* ctab  = ws;                    // 262400
  float* stab  = ctab + 262400;         // 262400
  float* pk    = stab + 262400;         // 262144
  float* pv    = pk + 262144;           // 262144
  float* qbuf  = pv + 262144;           // 65536
  float* apart = qbuf + 65536;          // 128*8*4*130 = 532480
  float* attn  = apart + 532480;        // 65536
  float* gpart = attn + 65536;          // 64*16*6144 = 6291456

  k_table<<<257, 256, 0, stream>>>(ctab, stab, pk, pv);
  // DIAGNOSTIC ROUND: qkv-gemm reps=10, attn reps=4 (idempotent re-execution)
  // to surface both kernels in rocprof top-5 and split cold/hot (HBM vs floor) time.
  k_gemm_part<<<dim3(QKV_COLS / 512, NSPLIT), 128, 0, stream>>>(hs, w_qkv, gpart, HIDDEN, QKV_COLS, 10);
  k_qkv_finish<<<(B_ * 3584) / 256, 256, 0, stream>>>(gpart, positions, ctab, stab, qbuf, pk, pv);
  k_attn<<<dim3(B_ * NKV, NCHUNK), 128, 0, stream>>>(kc, vc, bt, qbuf, pk, pv, ctab, stab, apart, 4);
  k_attn_combine<<<B_ * NKV, 512, 0, stream>>>(apart, attn);
  k_gemm_part<<<dim3(HIDDEN / 512, NSPLIT), 128, 0, stream>>>(attn, w_o, gpart, HIDDEN, HIDDEN, 1);
  k_reduce_out<<<(B_ * HIDDEN) / 256, 256, 0, stream>>>(gpart, out);
}

// Round 9
// 245.082 us; speedup vs baseline: 4.8901x; 4.8901x over previous
//
#include <hip/hip_runtime.h>
#include <math.h>

#define B_      16
#define NH      32
#define NKV     8
#define HD      128
#define GQ      4
#define LWIN    4096
#define BS      16
#define MAXB    385
#define HIDDEN  4096
#define QKV_COLS 6144
#define TAB_N   4100
#define T_CUR   4080      // window index of the current (new) token
#define KS      64        // k-rows per gemm split slice
#define NSPLIT  64        // number of k slices (4096/KS)
#define NCHUNK  8         // 512-token chunks
#define SCALE   0.088388347648318447f   // 128^-0.5
#define LOG1E4  9.210340371976184
#define TWO_PI  6.283185307179586
#define INV_2PI 0.15915494309189535

typedef float f4v __attribute__((ext_vector_type(4)));

// ---------------- K0: trig tables + zero patched blocks ----------------
__global__ void k_table(float* __restrict__ ctab, float* __restrict__ stab,
                        float* __restrict__ pk, float* __restrict__ pv) {
  int idx = blockIdx.x * 256 + threadIdx.x;
  if (idx < 64 * (TAB_N / 4)) {
    int d = idx / (TAB_N / 4);
    int q = idx - d * (TAB_N / 4);
    int i0 = q * 4;
    double f = exp(-(double)d / 64.0 * LOG1E4);
    double a = (double)(i0 - 1) * f;
    double rev = a * INV_2PI;
    rev -= rint(rev);
    float r = (float)(rev * TWO_PI);
    float c = cosf(r), s = sinf(r);
    float ff = (float)f;
    float cf = cosf(ff), sf = sinf(ff);
    int base = d * TAB_N + i0;
    ctab[base] = c; stab[base] = s;
#pragma unroll
    for (int j = 1; j < 4; j++) {
      float cn = c * cf - s * sf;
      float sn = s * cf + c * sf;
      c = cn; s = sn;
      ctab[base + j] = c; stab[base + j] = s;
    }
  }
  int nz = B_ * NKV * HD * BS;
  for (int z = idx; z < nz; z += gridDim.x * 256) { pk[z] = 0.f; pv[z] = 0.f; }
}

// ---------------- split-K skinny GEMM partial: part[ky][b][n] ----------------
// Deep pipeline: 16 W-row loads (64 VGPR) in flight before consumption.
__global__ __launch_bounds__(128, 1) void k_gemm_part(
    const float* __restrict__ X, const float* __restrict__ W,
    float* __restrict__ part, int K, int ncols) {
  int tid = threadIdx.x;
  int k0 = blockIdx.y * KS;
  int n4 = (blockIdx.x * 128 + tid) * 4;
  f4v acc[B_];
#pragma unroll
  for (int b = 0; b < B_; b++) acc[b] = (f4v){0.f, 0.f, 0.f, 0.f};
  const float* wp = W + (size_t)k0 * ncols + n4;
  const float* xp = X + k0;
#pragma unroll
  for (int batch = 0; batch < KS / 16; batch++) {
    f4v w[16];
#pragma unroll
    for (int i = 0; i < 16; i++)
      w[i] = __builtin_nontemporal_load((const f4v*)&wp[(size_t)(batch * 16 + i) * ncols]);
#pragma unroll
    for (int i = 0; i < 16; i++) {
      int kk = batch * 16 + i;
#pragma unroll
      for (int b = 0; b < B_; b++) {
        float x = xp[b * K + kk];
        acc[b][0] = fmaf(x, w[i][0], acc[b][0]);
        acc[b][1] = fmaf(x, w[i][1], acc[b][1]);
        acc[b][2] = fmaf(x, w[i][2], acc[b][2]);
        acc[b][3] = fmaf(x, w[i][3], acc[b][3]);
      }
    }
  }
  float* pp = part + (size_t)blockIdx.y * B_ * ncols + n4;
#pragma unroll
  for (int b = 0; b < B_; b++) *(f4v*)&pp[(size_t)b * ncols] = acc[b];
}

// ------------- reduce qkv partials + RoPE + scatter q / patched k,v -------------
__global__ __launch_bounds__(256) void k_qkv_finish(
    const float* __restrict__ part, const int* __restrict__ positions,
    const float* __restrict__ ctab, const float* __restrict__ stab,
    float* __restrict__ qout, float* __restrict__ pk, float* __restrict__ pv) {
  int idx = blockIdx.x * 256 + threadIdx.x;
  int b = idx / 3584;
  int u = idx - b * 3584;
  if (b >= B_) return;
  if (u < 2560) {                       // rope pair units: h in [0,40), j in [0,64)
    int h = u >> 6, j = u & 63;
    int c1 = h * 128 + j;
    int c2 = c1 + 64;
    float s1 = 0.f, s2 = 0.f;
#pragma unroll 8
    for (int ky = 0; ky < NSPLIT; ky++) {
      const float* p = part + ((size_t)ky * B_ + b) * QKV_COLS;
      s1 += p[c1];
      s2 += p[c2];
    }
    int pos = min(positions[b], LWIN - 1);
    float c = ctab[j * TAB_N + pos + 1];
    float s = stab[j * TAB_N + pos + 1];
    float o1 = s1 * c - s2 * s;
    float o2 = s2 * c + s1 * s;
    if (h < NH) {
      qout[b * HIDDEN + c1] = o1;
      qout[b * HIDDEN + c2] = o2;
    } else {
      int kv = h - NH;
      pk[((b * NKV + kv) * HD + j) * BS] = o1;
      pk[((b * NKV + kv) * HD + j + 64) * BS] = o2;
    }
  } else {                              // v units
    int vi = u - 2560;
    int kv = vi >> 7, d = vi & 127;
    int col = 5120 + vi;
    float s = 0.f;
#pragma unroll 8
    for (int ky = 0; ky < NSPLIT; ky++)
      s += part[((size_t)ky * B_ + b) * QKV_COLS + col];
    pv[((b * NKV + kv) * HD + d) * BS] = s;
  }
}

// ---------------- paged attention (R5 structure + deep load pipeline) ----------------
__global__ __launch_bounds__(128, 1) void k_attn(
    const float* __restrict__ kc, const float* __restrict__ vc,
    const int* __restrict__ bt, const float* __restrict__ qbuf,
    const float* __restrict__ pk, const float* __restrict__ pv,
    const float* __restrict__ ctab, const float* __restrict__ stab,
    float* __restrict__ partial) {
  __shared__ __align__(16) float qT[HD][GQ];      // [d][g]
  __shared__ __align__(16) float p_s[512][GQ];    // chunk-local probs
  __shared__ float redm[2][GQ];
  __shared__ float redl[2][GQ];
  __shared__ const float* kbase[32];
  __shared__ const float* vbase[32];

  int bx = blockIdx.x;
  int b = bx & 15, kv = bx >> 4;
  int chunk = blockIdx.y;   // 0..7, 512 tokens each
  int tid = threadIdx.x;
  int lane = tid & 63, wave = tid >> 6;

  for (int i = tid; i < GQ * HD; i += 128) {
    int g = i >> 7, d = i & 127;
    qT[d][g] = qbuf[b * HIDDEN + (kv * GQ + g) * HD + d];
  }
  if (tid < 32) {
    int tb = chunk * 32 + tid;          // global 16-token block index
    if (tb == 255) {
      kbase[tid] = pk + (size_t)(b * NKV + kv) * (HD * BS);
      vbase[tid] = pv + (size_t)(b * NKV + kv) * (HD * BS);
    } else {
      int lg = (tb == 0) ? 0 : (129 + tb);
      size_t off = ((size_t)bt[b * MAXB + lg] * NKV + kv) * (HD * BS);
      kbase[tid] = kc + off;
      vbase[tid] = vc + off;
    }
  }
  __syncthreads();

  // ---- phase A: scores, 256 tokens per wave; d in batches of 8 (32 loads in flight) ----
  int blk_i = lane & 15, qq = lane >> 4;
  int t0 = chunk * 512 + wave * 256 + blk_i * 16 + qq * 4;
  const float* kb = kbase[wave * 16 + blk_i] + qq * 4;
  bool rot = (t0 >= 16) && (t0 < T_CUR);
  const float* ctp = ctab + t0;
  const float* stp = stab + t0;

  float sc[GQ][4];
#pragma unroll
  for (int g = 0; g < GQ; g++)
#pragma unroll
    for (int c = 0; c < 4; c++) sc[g][c] = 0.f;

#pragma unroll
  for (int batch = 0; batch < 8; batch++) {
    f4v k1[8], k2[8], cv[8], sv[8];
#pragma unroll
    for (int i = 0; i < 8; i++) {
      int d = batch * 8 + i;
      k1[i] = __builtin_nontemporal_load((const f4v*)(kb + d * BS));
      k2[i] = __builtin_nontemporal_load((const f4v*)(kb + (d + 64) * BS));
      cv[i] = *(const f4v*)(ctp + d * TAB_N);
      sv[i] = *(const f4v*)(stp + d * TAB_N);
    }
#pragma unroll
    for (int i = 0; i < 8; i++) {
      int d = batch * 8 + i;
      float4 q1 = *(const float4*)&qT[d][0];
      float4 q2 = *(const float4*)&qT[d + 64][0];
      float qg1[4] = {q1.x, q1.y, q1.z, q1.w};
      float qg2[4] = {q2.x, q2.y, q2.z, q2.w};
#pragma unroll
      for (int c = 0; c < 4; c++) {
        float cc = rot ? cv[i][c] : 1.f;
        float ss = rot ? sv[i][c] : 0.f;
        float r1 = k1[i][c] * cc - k2[i][c] * ss;
        float r2 = k2[i][c] * cc + k1[i][c] * ss;
#pragma unroll
        for (int g = 0; g < GQ; g++)
          sc[g][c] = fmaf(qg1[g], r1, fmaf(qg2[g], r2, sc[g][c]));
      }
    }
  }

  // scale + validity mask + per-wave max
  float mloc[GQ];
#pragma unroll
  for (int g = 0; g < GQ; g++) {
    float m = -3e38f;
#pragma unroll
    for (int c = 0; c < 4; c++) {
      float s = (t0 + c <= T_CUR) ? sc[g][c] * SCALE : -3e38f;
      sc[g][c] = s;
      m = fmaxf(m, s);
    }
#pragma unroll
    for (int off = 1; off < 64; off <<= 1) m = fmaxf(m, __shfl_xor(m, off, 64));
    mloc[g] = m;
  }
  if (lane == 0) {
#pragma unroll
    for (int g = 0; g < GQ; g++) redm[wave][g] = mloc[g];
  }
  __syncthreads();
  float mb[GQ];
#pragma unroll
  for (int g = 0; g < GQ; g++) mb[g] = fmaxf(redm[0][g], redm[1][g]);

  // probs + per-wave sums
  float4 prc[4];
  float ls[GQ] = {0.f, 0.f, 0.f, 0.f};
#pragma unroll
  for (int c = 0; c < 4; c++) {
    float p0 = __expf(sc[0][c] - mb[0]);
    float p1 = __expf(sc[1][c] - mb[1]);
    float p2 = __expf(sc[2][c] - mb[2]);
    float p3 = __expf(sc[3][c] - mb[3]);
    ls[0] += p0; ls[1] += p1; ls[2] += p2; ls[3] += p3;
    prc[c] = make_float4(p0, p1, p2, p3);
  }
#pragma unroll
  for (int g = 0; g < GQ; g++) {
    float v = ls[g];
#pragma unroll
    for (int off = 1; off < 64; off <<= 1) v += __shfl_xor(v, off, 64);
    ls[g] = v;
  }
  if (lane == 0) {
#pragma unroll
    for (int g = 0; g < GQ; g++) redl[wave][g] = ls[g];
  }
  int trow = t0 - chunk * 512;
#pragma unroll
  for (int c = 0; c < 4; c++) *(float4*)&p_s[trow + c][0] = prc[c];
  __syncthreads();   // p_s / redl complete

  // ---- phase B: PV; V-blocks in batches of 4 (16 loads in flight) ----
  float acc0 = 0.f, acc1 = 0.f, acc2 = 0.f, acc3 = 0.f;
  int d_own = tid;   // 0..127
#pragma unroll
  for (int bt4 = 0; bt4 < 8; bt4++) {
    f4v vr[4][4];
#pragma unroll
    for (int t = 0; t < 4; t++) {
      const float* vb = vbase[bt4 * 4 + t] + d_own * BS;
      vr[t][0] = __builtin_nontemporal_load((const f4v*)(vb));
      vr[t][1] = __builtin_nontemporal_load((const f4v*)(vb + 4));
      vr[t][2] = __builtin_nontemporal_load((const f4v*)(vb + 8));
      vr[t][3] = __builtin_nontemporal_load((const f4v*)(vb + 12));
    }
#pragma unroll
    for (int t = 0; t < 4; t++) {
      const float* pp = &p_s[(bt4 * 4 + t) * 16][0];
#pragma unroll
      for (int jq = 0; jq < 4; jq++) {
#pragma unroll
        for (int j = 0; j < 4; j++) {
          float4 pj = *(const float4*)(pp + (jq * 4 + j) * GQ);
          float vv = vr[t][jq][j];
          acc0 = fmaf(pj.x, vv, acc0);
          acc1 = fmaf(pj.y, vv, acc1);
          acc2 = fmaf(pj.z, vv, acc2);
          acc3 = fmaf(pj.w, vv, acc3);
        }
      }
    }
  }

  int pid = b * NKV + kv;
  float* pw = partial + ((size_t)pid * NCHUNK + chunk) * (GQ * 130);
  pw[0 * 130 + 2 + d_own] = acc0;
  pw[1 * 130 + 2 + d_own] = acc1;
  pw[2 * 130 + 2 + d_own] = acc2;
  pw[3 * 130 + 2 + d_own] = acc3;
  if (tid == 0) {
#pragma unroll
    for (int g = 0; g < GQ; g++) {
      pw[g * 130 + 0] = mb[g];
      pw[g * 130 + 1] = redl[0][g] + redl[1][g];
    }
  }
}

// ---------------- combine chunk partials -> attn[b][h*128+d] ----------------
__global__ __launch_bounds__(512) void k_attn_combine(
    const float* __restrict__ partial, float* __restrict__ attn) {
  int pair = blockIdx.x;
  int tid = threadIdx.x;
  int g = tid >> 7, d = tid & 127;
  const float* pb = partial + (size_t)pair * NCHUNK * (GQ * 130) + g * 130;
  float M = -3e38f;
#pragma unroll
  for (int c = 0; c < NCHUNK; c++) M = fmaxf(M, pb[c * (GQ * 130)]);
  float L = 0.f, val = 0.f;
#pragma unroll
  for (int c = 0; c < NCHUNK; c++) {
    float m = pb[c * (GQ * 130)];
    float l = pb[c * (GQ * 130) + 1];
    float a = pb[c * (GQ * 130) + 2 + d];
    float w = __expf(m - M);
    L += l * w;
    val = fmaf(a, w, val);
  }
  int b = pair >> 3, kv = pair & 7;
  attn[b * HIDDEN + (kv * GQ + g) * HD + d] = val / L;
}

// ---------------- reduce w_o partials -> out ----------------
__global__ __launch_bounds__(256) void k_reduce_out(
    const float* __restrict__ part, float* __restrict__ out) {
  int idx = blockIdx.x * 256 + threadIdx.x;
  int b = idx >> 12, n = idx & 4095;
  float s = 0.f;
#pragma unroll 8
  for (int ky = 0; ky < NSPLIT; ky++)
    s += part[((size_t)ky * B_ + b) * HIDDEN + n];
  out[idx] = s;
}

extern "C" void kernel_launch(void* const* d_in, const int* in_sizes, int n_in,
                              void* d_out, int out_size, void* d_ws, size_t ws_size,
                              hipStream_t stream) {
  const int*   positions = (const int*)d_in[0];
  const float* hs        = (const float*)d_in[1];
  const float* kc        = (const float*)d_in[2];
  const float* vc        = (const float*)d_in[3];
  const int*   bt        = (const int*)d_in[4];
  const float* w_qkv     = (const float*)d_in[6];
  const float* w_o       = (const float*)d_in[7];
  float* out = (float*)d_out;

  float* ws    = (float*)d_ws;
  float* ctab  = ws;                    // 262400
  float* stab  = ctab + 262400;         // 262400
  float* pk    = stab + 262400;         // 262144
  float* pv    = pk + 262144;           // 262144
  float* qbuf  = pv + 262144;           // 65536
  float* apart = qbuf + 65536;          // 128*8*4*130 = 532480
  float* attn  = apart + 532480;        // 65536
  float* gpart = attn + 65536;          // 64*16*6144 = 6291456

  k_table<<<257, 256, 0, stream>>>(ctab, stab, pk, pv);
  k_gemm_part<<<dim3(QKV_COLS / 512, NSPLIT), 128, 0, stream>>>(hs, w_qkv, gpart, HIDDEN, QKV_COLS);
  k_qkv_finish<<<(B_ * 3584) / 256, 256, 0, stream>>>(gpart, positions, ctab, stab, qbuf, pk, pv);
  k_attn<<<dim3(B_ * NKV, NCHUNK), 128, 0, stream>>>(kc, vc, bt, qbuf, pk, pv, ctab, stab, apart);
  k_attn_combine<<<B_ * NKV, 512, 0, stream>>>(apart, attn);
  k_gemm_part<<<dim3(HIDDEN / 512, NSPLIT), 128, 0, stream>>>(attn, w_o, gpart, HIDDEN, HIDDEN);
  k_reduce_out<<<(B_ * HIDDEN) / 256, 256, 0, stream>>>(gpart, out);
}

// Round 10
// 216.714 us; speedup vs baseline: 5.5302x; 1.1309x over previous
//
#include <hip/hip_runtime.h>
#include <math.h>

#define B_      16
#define NH      32
#define NKV     8
#define HD      128
#define GQ      4
#define LWIN    4096
#define BS      16
#define MAXB    385
#define HIDDEN  4096
#define QKV_COLS 6144
#define TAB_N   4100
#define T_CUR   4080      // window index of the current (new) token
#define KS      64        // k-rows per gemm split slice
#define NSPLIT  64        // number of k slices (4096/KS)
#define NCHUNK  8         // 512-token chunks
#define SCALE   0.088388347648318447f   // 128^-0.5
#define LOG1E4  9.210340371976184
#define TWO_PI  6.283185307179586
#define INV_2PI 0.15915494309189535

typedef float f4v __attribute__((ext_vector_type(4)));

// ---------------- K0: trig tables + zero patched blocks ----------------
__global__ void k_table(float* __restrict__ ctab, float* __restrict__ stab,
                        float* __restrict__ pk, float* __restrict__ pv) {
  int idx = blockIdx.x * 256 + threadIdx.x;
  if (idx < 64 * (TAB_N / 4)) {
    int d = idx / (TAB_N / 4);
    int q = idx - d * (TAB_N / 4);
    int i0 = q * 4;
    double f = exp(-(double)d / 64.0 * LOG1E4);
    double a = (double)(i0 - 1) * f;
    double rev = a * INV_2PI;
    rev -= rint(rev);
    float r = (float)(rev * TWO_PI);
    float c = cosf(r), s = sinf(r);
    float ff = (float)f;
    float cf = cosf(ff), sf = sinf(ff);
    int base = d * TAB_N + i0;
    ctab[base] = c; stab[base] = s;
#pragma unroll
    for (int j = 1; j < 4; j++) {
      float cn = c * cf - s * sf;
      float sn = s * cf + c * sf;
      c = cn; s = sn;
      ctab[base + j] = c; stab[base + j] = s;
    }
  }
  int nz = B_ * NKV * HD * BS;
  for (int z = idx; z < nz; z += gridDim.x * 256) { pk[z] = 0.f; pv[z] = 0.f; }
}

// ---------------- split-K skinny GEMM partial: part[ky][b][n] ----------------
// Deep pipeline: 16 W-row loads (64 VGPR) in flight before consumption.
__global__ __launch_bounds__(128, 1) void k_gemm_part(
    const float* __restrict__ X, const float* __restrict__ W,
    float* __restrict__ part, int K, int ncols) {
  int tid = threadIdx.x;
  int k0 = blockIdx.y * KS;
  int n4 = (blockIdx.x * 128 + tid) * 4;
  f4v acc[B_];
#pragma unroll
  for (int b = 0; b < B_; b++) acc[b] = (f4v){0.f, 0.f, 0.f, 0.f};
  const float* wp = W + (size_t)k0 * ncols + n4;
  const float* xp = X + k0;
#pragma unroll
  for (int batch = 0; batch < KS / 16; batch++) {
    f4v w[16];
#pragma unroll
    for (int i = 0; i < 16; i++)
      w[i] = *(const f4v*)&wp[(size_t)(batch * 16 + i) * ncols];
#pragma unroll
    for (int i = 0; i < 16; i++) {
      int kk = batch * 16 + i;
#pragma unroll
      for (int b = 0; b < B_; b++) {
        float x = xp[b * K + kk];
        acc[b][0] = fmaf(x, w[i][0], acc[b][0]);
        acc[b][1] = fmaf(x, w[i][1], acc[b][1]);
        acc[b][2] = fmaf(x, w[i][2], acc[b][2]);
        acc[b][3] = fmaf(x, w[i][3], acc[b][3]);
      }
    }
  }
  float* pp = part + (size_t)blockIdx.y * B_ * ncols + n4;
#pragma unroll
  for (int b = 0; b < B_; b++) *(f4v*)&pp[(size_t)b * ncols] = acc[b];
}

// ------------- reduce qkv partials + RoPE + scatter q / patched k,v -------------
__global__ __launch_bounds__(256) void k_qkv_finish(
    const float* __restrict__ part, const int* __restrict__ positions,
    const float* __restrict__ ctab, const float* __restrict__ stab,
    float* __restrict__ qout, float* __restrict__ pk, float* __restrict__ pv) {
  int idx = blockIdx.x * 256 + threadIdx.x;
  int b = idx / 3584;
  int u = idx - b * 3584;
  if (b >= B_) return;
  if (u < 2560) {                       // rope pair units: h in [0,40), j in [0,64)
    int h = u >> 6, j = u & 63;
    int c1 = h * 128 + j;
    int c2 = c1 + 64;
    float s1 = 0.f, s2 = 0.f;
#pragma unroll 8
    for (int ky = 0; ky < NSPLIT; ky++) {
      const float* p = part + ((size_t)ky * B_ + b) * QKV_COLS;
      s1 += p[c1];
      s2 += p[c2];
    }
    int pos = min(positions[b], LWIN - 1);
    float c = ctab[j * TAB_N + pos + 1];
    float s = stab[j * TAB_N + pos + 1];
    float o1 = s1 * c - s2 * s;
    float o2 = s2 * c + s1 * s;
    if (h < NH) {
      qout[b * HIDDEN + c1] = o1;
      qout[b * HIDDEN + c2] = o2;
    } else {
      int kv = h - NH;
      pk[((b * NKV + kv) * HD + j) * BS] = o1;
      pk[((b * NKV + kv) * HD + j + 64) * BS] = o2;
    }
  } else {                              // v units
    int vi = u - 2560;
    int kv = vi >> 7, d = vi & 127;
    int col = 5120 + vi;
    float s = 0.f;
#pragma unroll 8
    for (int ky = 0; ky < NSPLIT; ky++)
      s += part[((size_t)ky * B_ + b) * QKV_COLS + col];
    pv[((b * NKV + kv) * HD + d) * BS] = s;
  }
}

// ---------------- paged attention (R5 structure + deep load pipeline) ----------------
__global__ __launch_bounds__(128, 1) void k_attn(
    const float* __restrict__ kc, const float* __restrict__ vc,
    const int* __restrict__ bt, const float* __restrict__ qbuf,
    const float* __restrict__ pk, const float* __restrict__ pv,
    const float* __restrict__ ctab, const float* __restrict__ stab,
    float* __restrict__ partial) {
  __shared__ __align__(16) float qT[HD][GQ];      // [d][g]
  __shared__ __align__(16) float p_s[512][GQ];    // chunk-local probs
  __shared__ float redm[2][GQ];
  __shared__ float redl[2][GQ];
  __shared__ const float* kbase[32];
  __shared__ const float* vbase[32];

  int bx = blockIdx.x;
  int b = bx & 15, kv = bx >> 4;
  int chunk = blockIdx.y;   // 0..7, 512 tokens each
  int tid = threadIdx.x;
  int lane = tid & 63, wave = tid >> 6;

  for (int i = tid; i < GQ * HD; i += 128) {
    int g = i >> 7, d = i & 127;
    qT[d][g] = qbuf[b * HIDDEN + (kv * GQ + g) * HD + d];
  }
  if (tid < 32) {
    int tb = chunk * 32 + tid;          // global 16-token block index
    if (tb == 255) {
      kbase[tid] = pk + (size_t)(b * NKV + kv) * (HD * BS);
      vbase[tid] = pv + (size_t)(b * NKV + kv) * (HD * BS);
    } else {
      int lg = (tb == 0) ? 0 : (129 + tb);
      size_t off = ((size_t)bt[b * MAXB + lg] * NKV + kv) * (HD * BS);
      kbase[tid] = kc + off;
      vbase[tid] = vc + off;
    }
  }
  __syncthreads();

  // ---- phase A: scores, 256 tokens per wave; d in batches of 8 (32 loads in flight) ----
  int blk_i = lane & 15, qq = lane >> 4;
  int t0 = chunk * 512 + wave * 256 + blk_i * 16 + qq * 4;
  const float* kb = kbase[wave * 16 + blk_i] + qq * 4;
  bool rot = (t0 >= 16) && (t0 < T_CUR);
  const float* ctp = ctab + t0;
  const float* stp = stab + t0;

  float sc[GQ][4];
#pragma unroll
  for (int g = 0; g < GQ; g++)
#pragma unroll
    for (int c = 0; c < 4; c++) sc[g][c] = 0.f;

#pragma unroll
  for (int batch = 0; batch < 8; batch++) {
    f4v k1[8], k2[8], cv[8], sv[8];
#pragma unroll
    for (int i = 0; i < 8; i++) {
      int d = batch * 8 + i;
      k1[i] = *(const f4v*)(kb + d * BS);
      k2[i] = *(const f4v*)(kb + (d + 64) * BS);
      cv[i] = *(const f4v*)(ctp + d * TAB_N);
      sv[i] = *(const f4v*)(stp + d * TAB_N);
    }
#pragma unroll
    for (int i = 0; i < 8; i++) {
      int d = batch * 8 + i;
      float4 q1 = *(const float4*)&qT[d][0];
      float4 q2 = *(const float4*)&qT[d + 64][0];
      float qg1[4] = {q1.x, q1.y, q1.z, q1.w};
      float qg2[4] = {q2.x, q2.y, q2.z, q2.w};
#pragma unroll
      for (int c = 0; c < 4; c++) {
        float cc = rot ? cv[i][c] : 1.f;
        float ss = rot ? sv[i][c] : 0.f;
        float r1 = k1[i][c] * cc - k2[i][c] * ss;
        float r2 = k2[i][c] * cc + k1[i][c] * ss;
#pragma unroll
        for (int g = 0; g < GQ; g++)
          sc[g][c] = fmaf(qg1[g], r1, fmaf(qg2[g], r2, sc[g][c]));
      }
    }
  }

  // scale + validity mask + per-wave max
  float mloc[GQ];
#pragma unroll
  for (int g = 0; g < GQ; g++) {
    float m = -3e38f;
#pragma unroll
    for (int c = 0; c < 4; c++) {
      float s = (t0 + c <= T_CUR) ? sc[g][c] * SCALE : -3e38f;
      sc[g][c] = s;
      m = fmaxf(m, s);
    }
#pragma unroll
    for (int off = 1; off < 64; off <<= 1) m = fmaxf(m, __shfl_xor(m, off, 64));
    mloc[g] = m;
  }
  if (lane == 0) {
#pragma unroll
    for (int g = 0; g < GQ; g++) redm[wave][g] = mloc[g];
  }
  __syncthreads();
  float mb[GQ];
#pragma unroll
  for (int g = 0; g < GQ; g++) mb[g] = fmaxf(redm[0][g], redm[1][g]);

  // probs + per-wave sums
  float4 prc[4];
  float ls[GQ] = {0.f, 0.f, 0.f, 0.f};
#pragma unroll
  for (int c = 0; c < 4; c++) {
    float p0 = __expf(sc[0][c] - mb[0]);
    float p1 = __expf(sc[1][c] - mb[1]);
    float p2 = __expf(sc[2][c] - mb[2]);
    float p3 = __expf(sc[3][c] - mb[3]);
    ls[0] += p0; ls[1] += p1; ls[2] += p2; ls[3] += p3;
    prc[c] = make_float4(p0, p1, p2, p3);
  }
#pragma unroll
  for (int g = 0; g < GQ; g++) {
    float v = ls[g];
#pragma unroll
    for (int off = 1; off < 64; off <<= 1) v += __shfl_xor(v, off, 64);
    ls[g] = v;
  }
  if (lane == 0) {
#pragma unroll
    for (int g = 0; g < GQ; g++) redl[wave][g] = ls[g];
  }
  int trow = t0 - chunk * 512;
#pragma unroll
  for (int c = 0; c < 4; c++) *(float4*)&p_s[trow + c][0] = prc[c];
  __syncthreads();   // p_s / redl complete

  // ---- phase B: PV; V-blocks in batches of 4 (16 loads in flight) ----
  float acc0 = 0.f, acc1 = 0.f, acc2 = 0.f, acc3 = 0.f;
  int d_own = tid;   // 0..127
#pragma unroll
  for (int bt4 = 0; bt4 < 8; bt4++) {
    f4v vr[4][4];
#pragma unroll
    for (int t = 0; t < 4; t++) {
      const float* vb = vbase[bt4 * 4 + t] + d_own * BS;
      vr[t][0] = *(const f4v*)(vb);
      vr[t][1] = *(const f4v*)(vb + 4);
      vr[t][2] = *(const f4v*)(vb + 8);
      vr[t][3] = *(const f4v*)(vb + 12);
    }
#pragma unroll
    for (int t = 0; t < 4; t++) {
      const float* pp = &p_s[(bt4 * 4 + t) * 16][0];
#pragma unroll
      for (int jq = 0; jq < 4; jq++) {
#pragma unroll
        for (int j = 0; j < 4; j++) {
          float4 pj = *(const float4*)(pp + (jq * 4 + j) * GQ);
          float vv = vr[t][jq][j];
          acc0 = fmaf(pj.x, vv, acc0);
          acc1 = fmaf(pj.y, vv, acc1);
          acc2 = fmaf(pj.z, vv, acc2);
          acc3 = fmaf(pj.w, vv, acc3);
        }
      }
    }
  }

  int pid = b * NKV + kv;
  float* pw = partial + ((size_t)pid * NCHUNK + chunk) * (GQ * 130);
  pw[0 * 130 + 2 + d_own] = acc0;
  pw[1 * 130 + 2 + d_own] = acc1;
  pw[2 * 130 + 2 + d_own] = acc2;
  pw[3 * 130 + 2 + d_own] = acc3;
  if (tid == 0) {
#pragma unroll
    for (int g = 0; g < GQ; g++) {
      pw[g * 130 + 0] = mb[g];
      pw[g * 130 + 1] = redl[0][g] + redl[1][g];
    }
  }
}

// ---------------- combine chunk partials -> attn[b][h*128+d] ----------------
__global__ __launch_bounds__(512) void k_attn_combine(
    const float* __restrict__ partial, float* __restrict__ attn) {
  int pair = blockIdx.x;
  int tid = threadIdx.x;
  int g = tid >> 7, d = tid & 127;
  const float* pb = partial + (size_t)pair * NCHUNK * (GQ * 130) + g * 130;
  float M = -3e38f;
#pragma unroll
  for (int c = 0; c < NCHUNK; c++) M = fmaxf(M, pb[c * (GQ * 130)]);
  float L = 0.f, val = 0.f;
#pragma unroll
  for (int c = 0; c < NCHUNK; c++) {
    float m = pb[c * (GQ * 130)];
    float l = pb[c * (GQ * 130) + 1];
    float a = pb[c * (GQ * 130) + 2 + d];
    float w = __expf(m - M);
    L += l * w;
    val = fmaf(a, w, val);
  }
  int b = pair >> 3, kv = pair & 7;
  attn[b * HIDDEN + (kv * GQ + g) * HD + d] = val / L;
}

// ---------------- reduce w_o partials -> out ----------------
__global__ __launch_bounds__(256) void k_reduce_out(
    const float* __restrict__ part, float* __restrict__ out) {
  int idx = blockIdx.x * 256 + threadIdx.x;
  int b = idx >> 12, n = idx & 4095;
  float s = 0.f;
#pragma unroll 8
  for (int ky = 0; ky < NSPLIT; ky++)
    s += part[((size_t)ky * B_ + b) * HIDDEN + n];
  out[idx] = s;
}

extern "C" void kernel_launch(void* const* d_in, const int* in_sizes, int n_in,
                              void* d_out, int out_size, void* d_ws, size_t ws_size,
                              hipStream_t stream) {
  const int*   positions = (const int*)d_in[0];
  const float* hs        = (const float*)d_in[1];
  const float* kc        = (const float*)d_in[2];
  const float* vc        = (const float*)d_in[3];
  const int*   bt        = (const int*)d_in[4];
  const float* w_qkv     = (const float*)d_in[6];
  const float* w_o       = (const float*)d_in[7];
  float* out = (float*)d_out;

  float* ws    = (float*)d_ws;
  float* ctab  = ws;                    // 262400
  float* stab  = ctab + 262400;         // 262400
  float* pk    = stab + 262400;         // 262144
  float* pv    = pk + 262144;           // 262144
  float* qbuf  = pv + 262144;           // 65536
  float* apart = qbuf + 65536;          // 128*8*4*130 = 532480
  float* attn  = apart + 532480;        // 65536
  float* gpart = attn + 65536;          // 64*16*6144 = 6291456

  k_table<<<257, 256, 0, stream>>>(ctab, stab, pk, pv);
  k_gemm_part<<<dim3(QKV_COLS / 512, NSPLIT), 128, 0, stream>>>(hs, w_qkv, gpart, HIDDEN, QKV_COLS);
  k_qkv_finish<<<(B_ * 3584) / 256, 256, 0, stream>>>(gpart, positions, ctab, stab, qbuf, pk, pv);
  k_attn<<<dim3(B_ * NKV, NCHUNK), 128, 0, stream>>>(kc, vc, bt, qbuf, pk, pv, ctab, stab, apart);
  k_attn_combine<<<B_ * NKV, 512, 0, stream>>>(apart, attn);
  k_gemm_part<<<dim3(HIDDEN / 512, NSPLIT), 128, 0, stream>>>(attn, w_o, gpart, HIDDEN, HIDDEN);
  k_reduce_out<<<(B_ * HIDDEN) / 256, 256, 0, stream>>>(gpart, out);
}